// Round 7
// baseline (291.781 us; speedup 1.0000x reference)
//
#include <hip/hip_runtime.h>
#include <math.h>

// GeoAttention on gfx950: B=2, S=2048, DIM=512, H=8, HD=64.
// bf16 MFMA (16x16x32) everywhere, fp32 accumulate.
// R6: attn software-pipelined at the jt level — transform(jt+1) and PV(jt)
// are independent blocks in one BB (scheduler interleaves VALU with MFMA);
// per-wave double-buffered LDS P slices; 16-row waves, grid 2048 blocks.

typedef __attribute__((ext_vector_type(8))) short short8;
typedef __attribute__((ext_vector_type(4))) float f32x4;

#define MFMA(a, b, c) __builtin_amdgcn_mfma_f32_16x16x32_bf16((a), (b), (c), 0, 0, 0)

static __device__ __forceinline__ short f2bf(float f) {
    unsigned u = __float_as_uint(f);
    u += 0x7fffu + ((u >> 16) & 1u);          // round-to-nearest-even
    return (short)(u >> 16);
}
static __device__ __forceinline__ short f2bf_trunc(float f) {
    return (short)(__float_as_uint(f) >> 16); // bias cancels in num/den ratio
}

// ---------------------------------------------------------------------------
// Prep 1: xb[4096][1024] bf16 = concat(x_real, x_imag)
// ---------------------------------------------------------------------------
__global__ __launch_bounds__(256) void convert_x(
    const float* __restrict__ xr, const float* __restrict__ xi,
    short* __restrict__ xb)
{
    int idx = blockIdx.x * 256 + threadIdx.x;
    int e = idx << 2;
    int m = e >> 10, k = e & 1023;
    const float* src = (k < 512) ? xr : xi;
    float4 t = *(const float4*)(src + (size_t)m * 512 + (k & 511));
    unsigned lo = (unsigned short)f2bf(t.x) | ((unsigned)(unsigned short)f2bf(t.y) << 16);
    unsigned hi = (unsigned short)f2bf(t.z) | ((unsigned)(unsigned short)f2bf(t.w) << 16);
    uint2 o; o.x = lo; o.y = hi;
    *(uint2*)(xb + e) = o;
}

// ---------------------------------------------------------------------------
// Prep 2: transpose + convert weights to bf16, n-major [N][K].
// ---------------------------------------------------------------------------
__global__ __launch_bounds__(256) void transpose_w(
    const float* __restrict__ Wq, const float* __restrict__ Wk,
    const float* __restrict__ Wv, const float* __restrict__ Wo,
    short* __restrict__ wqt, short* __restrict__ wkt,
    short* __restrict__ wvt, short* __restrict__ wot)
{
    __shared__ float t[32][33];
    const int z = blockIdx.z;
    const float* src = (z == 0) ? Wq : (z == 1) ? Wk : (z == 2) ? Wv : Wo;
    short* dst = (z == 0) ? wqt : (z == 1) ? wkt : (z == 2) ? wvt : wot;
    const int K = (z < 3) ? 1024 : 512;
    const int N = (z < 3) ? 512 : 1024;
    const int n0 = blockIdx.x << 5, k0 = blockIdx.y << 5;
    if (n0 >= N || k0 >= K) return;
    const int tx = threadIdx.x & 31, ty = threadIdx.x >> 5;
    #pragma unroll
    for (int i = 0; i < 4; ++i)
        t[ty + 8 * i][tx] = src[(size_t)(k0 + ty + 8 * i) * N + n0 + tx];
    __syncthreads();
    #pragma unroll
    for (int i = 0; i < 4; ++i)
        dst[(size_t)(n0 + ty + 8 * i) * K + k0 + tx] = f2bf(t[tx][ty + 8 * i]);
}

// ---------------------------------------------------------------------------
// Kernel 1: QKV projection + fused softmax(64)+sqrt epilogue.
// 128-thr blocks = 2 waves; wave = 64 rows x 64 cols (16 MFMA per 8 loads).
// ---------------------------------------------------------------------------
__global__ __launch_bounds__(128) void qkv_mfma(
    const short* __restrict__ xb,
    const short* __restrict__ wqt, const short* __restrict__ wkt,
    const short* __restrict__ wvt,
    const float* __restrict__ bq, const float* __restrict__ bk,
    const float* __restrict__ bv,
    short* __restrict__ sp, short* __restrict__ sq, short* __restrict__ vt)
{
    __shared__ short vbuf[2][64 * 72];        // per-wave [d=64][s=64 +pad8]
    const int iwb = blockIdx.x;
    const int iw = iwb >> 3;
    const int h  = iwb & 7;
    const int tid = threadIdx.x;
    const int w = tid >> 6, lane = tid & 63;
    const int l = lane & 15, quad = lane >> 4;
    const int m0 = blockIdx.y * 128 + w * 64;

    const short* wt   = (iw == 0) ? wqt : (iw == 1) ? wkt : wvt;
    const float* bias = (iw == 0) ? bq  : (iw == 1) ? bk  : bv;
    short* dst        = (iw == 0) ? sp  : (iw == 1) ? sq  : vt;

    const short* ap[4];
    const short* bp[4];
    #pragma unroll
    for (int i = 0; i < 4; ++i)
        ap[i] = xb + (size_t)(m0 + i * 16 + l) * 1024 + quad * 8;
    #pragma unroll
    for (int j = 0; j < 4; ++j)
        bp[j] = wt + (size_t)(h * 64 + j * 16 + l) * 1024 + quad * 8;

    const f32x4 z4 = {0.f, 0.f, 0.f, 0.f};
    f32x4 acc[4][4];
    #pragma unroll
    for (int i = 0; i < 4; ++i)
        #pragma unroll
        for (int j = 0; j < 4; ++j) acc[i][j] = z4;

    short8 Af[4], Bf[4], Ag[4], Bg[4];
    #pragma unroll
    for (int i = 0; i < 4; ++i) { Af[i] = *(const short8*)ap[i]; Bf[i] = *(const short8*)bp[i]; }

    #pragma unroll 1
    for (int kc = 0; kc < 32; kc += 2) {
        const int ko1 = (kc + 1) * 32;
        #pragma unroll
        for (int i = 0; i < 4; ++i) {
            Ag[i] = *(const short8*)(ap[i] + ko1);
            Bg[i] = *(const short8*)(bp[i] + ko1);
        }
        #pragma unroll
        for (int i = 0; i < 4; ++i)
            #pragma unroll
            for (int j = 0; j < 4; ++j)
                acc[i][j] = MFMA(Af[i], Bf[j], acc[i][j]);
        const int ko2 = (kc + 2 < 32) ? (kc + 2) * 32 : 0;   // wrap: harmless
        #pragma unroll
        for (int i = 0; i < 4; ++i) {
            Af[i] = *(const short8*)(ap[i] + ko2);
            Bf[i] = *(const short8*)(bp[i] + ko2);
        }
        #pragma unroll
        for (int i = 0; i < 4; ++i)
            #pragma unroll
            for (int j = 0; j < 4; ++j)
                acc[i][j] = MFMA(Ag[i], Bg[j], acc[i][j]);
    }

    float bcol[4];
    #pragma unroll
    for (int nt = 0; nt < 4; ++nt) bcol[nt] = bias[h * 64 + nt * 16 + l];

    #pragma unroll
    for (int i = 0; i < 4; ++i) {
        #pragma unroll
        for (int reg = 0; reg < 4; ++reg) {
            const int sg = m0 + i * 16 + quad * 4 + reg;     // global row
            const int b = sg >> 11, s = sg & 2047;
            float v[4];
            #pragma unroll
            for (int nt = 0; nt < 4; ++nt) v[nt] = acc[i][nt][reg] + bcol[nt];
            if (iw < 2) {
                float mx = fmaxf(fmaxf(v[0], v[1]), fmaxf(v[2], v[3]));
                #pragma unroll
                for (int msk = 1; msk < 16; msk <<= 1) mx = fmaxf(mx, __shfl_xor(mx, msk));
                float e[4], ssum = 0.f;
                #pragma unroll
                for (int nt = 0; nt < 4; ++nt) { e[nt] = __expf(v[nt] - mx); ssum += e[nt]; }
                #pragma unroll
                for (int msk = 1; msk < 16; msk <<= 1) ssum += __shfl_xor(ssum, msk);
                float inv = 1.0f / ssum;
                short* o = dst + ((size_t)(b * 8 + h) * 2048 + s) * 64 + l;
                #pragma unroll
                for (int nt = 0; nt < 4; ++nt)
                    o[nt * 16] = f2bf(sqrtf(e[nt] * inv));
            } else {
                const int sl = i * 16 + quad * 4 + reg;      // local s in [0,64)
                #pragma unroll
                for (int nt = 0; nt < 4; ++nt)
                    vbuf[w][(nt * 16 + l) * 72 + sl] = f2bf(v[nt]);
            }
        }
    }

    if (iw == 2) {
        const int d = lane;
        const short* row = &vbuf[w][d * 72];
        const int b = m0 >> 11, s0 = m0 & 2047;
        short* gp = vt + ((size_t)(b * 8 + h) * 64 + d) * 2048 + s0;
        #pragma unroll
        for (int r = 0; r < 8; ++r)
            *(short8*)(gp + r * 8) = *(const short8*)(row + r * 8);
    }
}

// ---------------------------------------------------------------------------
// Kernel 2: attention. Grid (128, 16), 256 threads = 4 waves.
// Block = 16 Q-rows; wave w = j-quarter (512 j, 8 jt of 64).
// jt-level SW pipeline: body does pa-read(jt) | V-loads(jt) | QK(jt+1) |
// sq-prefetch(jt+2) | PV(jt) | transform(jt+1) -> all one BB, scheduler
// interleaves transform VALU with PV MFMA. Double-buffered per-wave LDS P.
// ---------------------------------------------------------------------------
__global__ __launch_bounds__(256) void attn_mfma(
    const short* __restrict__ sp, const short* __restrict__ sq,
    const short* __restrict__ vt, short* __restrict__ attB)
{
    __shared__ short Ps[4][2][16 * 72];         // 18,432 B (reused fp32 combine)
    __shared__ float denB[4][16];               // 256 B
    const int bh = blockIdx.y;
    const int m0 = blockIdx.x << 4;             // 16 Q-rows per block
    const int tid = threadIdx.x;
    const int w = tid >> 6, lane = tid & 63;
    const int l = lane & 15, quad = lane >> 4;

    const short* spB = sp + (size_t)bh * 2048 * 64;
    const short* sqB = sq + (size_t)bh * 2048 * 64 + (size_t)(w * 512) * 64;
    const short* vtB = vt + (size_t)bh * 64 * 2048 + w * 512;

    const short* aP = spB + (size_t)(m0 + l) * 64 + quad * 8;
    short8 aq0 = *(const short8*)(aP);
    short8 aq1 = *(const short8*)(aP + 32);

    const f32x4 z4 = {0.f, 0.f, 0.f, 0.f};
    f32x4 acc[4] = {z4, z4, z4, z4};
    float den[4] = {0.f, 0.f, 0.f, 0.f};

    // sq frags for jt=0
    short8 sqb[4][2];
    #pragma unroll
    for (int nt = 0; nt < 4; ++nt) {
        const short* q = sqB + (size_t)(nt * 16 + l) * 64 + quad * 8;
        sqb[nt][0] = *(const short8*)(q);
        sqb[nt][1] = *(const short8*)(q + 32);
    }

    // prologue: QK(0) -> transform -> buf0; prefetch sq(1)
    {
        f32x4 pn[4];
        #pragma unroll
        for (int nt = 0; nt < 4; ++nt) {
            pn[nt] = MFMA(aq0, sqb[nt][0], z4);
            pn[nt] = MFMA(aq1, sqb[nt][1], pn[nt]);
        }
        const short* sqn = sqB + (size_t)(1 * 64) * 64;
        #pragma unroll
        for (int nt = 0; nt < 4; ++nt) {
            const short* q = sqn + (size_t)(nt * 16 + l) * 64 + quad * 8;
            sqb[nt][0] = *(const short8*)(q);
            sqb[nt][1] = *(const short8*)(q + 32);
        }
        short* P0 = &Ps[w][0][0];
        #pragma unroll
        for (int nt = 0; nt < 4; ++nt)
            #pragma unroll
            for (int reg = 0; reg < 4; ++reg) {
                float u = fmaxf(1.0f - pn[nt][reg], 0.0f);
                float t = 0.000922f;
                t = fmaf(t, u, 0.00152228f);
                t = fmaf(t, u, 0.00384801f);
                t = fmaf(t, u, 0.01015873f);
                t = fmaf(t, u, 0.02857143f);
                t = fmaf(t, u, 0.08888889f);
                t = fmaf(t, u, 0.33333333f);
                t = fmaf(t, u, 2.0f);
                float wv = __expf(-u * t);
                den[reg] += wv;
                P0[(quad * 4 + reg) * 72 + nt * 16 + l] = f2bf_trunc(wv);
            }
    }

    #pragma unroll 1
    for (int jt = 0; jt < 7; ++jt) {
        short* Pc  = &Ps[w][jt & 1][0];
        short* Pnx = &Ps[w][(jt + 1) & 1][0];
        // pa frags of P(jt)
        const short* pr = Pc + l * 72 + quad * 8;
        short8 pa0 = *(const short8*)(pr);
        short8 pa1 = *(const short8*)(pr + 32);
        // V loads for jt
        short8 vb[4][2];
        const short* vj = vtB + jt * 64;
        #pragma unroll
        for (int nt = 0; nt < 4; ++nt) {
            const short* q = vj + (size_t)(nt * 16 + l) * 2048 + quad * 8;
            vb[nt][0] = *(const short8*)(q);
            vb[nt][1] = *(const short8*)(q + 32);
        }
        // QK(jt+1)
        f32x4 p2[4];
        #pragma unroll
        for (int nt = 0; nt < 4; ++nt) {
            p2[nt] = MFMA(aq0, sqb[nt][0], z4);
            p2[nt] = MFMA(aq1, sqb[nt][1], p2[nt]);
        }
        // prefetch sq(jt+2) (wrap: harmless re-read)
        const short* sqn = sqB + (size_t)(((jt + 2) & 7) * 64) * 64;
        #pragma unroll
        for (int nt = 0; nt < 4; ++nt) {
            const short* q = sqn + (size_t)(nt * 16 + l) * 64 + quad * 8;
            sqb[nt][0] = *(const short8*)(q);
            sqb[nt][1] = *(const short8*)(q + 32);
        }
        // PV(jt)  [MFMA] — independent of transform(jt+1) below [VALU]
        #pragma unroll
        for (int nt = 0; nt < 4; ++nt) {
            acc[nt] = MFMA(pa0, vb[nt][0], acc[nt]);
            acc[nt] = MFMA(pa1, vb[nt][1], acc[nt]);
        }
        // transform(jt+1) -> other buffer
        #pragma unroll
        for (int nt = 0; nt < 4; ++nt)
            #pragma unroll
            for (int reg = 0; reg < 4; ++reg) {
                float u = fmaxf(1.0f - p2[nt][reg], 0.0f);
                float t = 0.000922f;
                t = fmaf(t, u, 0.00152228f);
                t = fmaf(t, u, 0.00384801f);
                t = fmaf(t, u, 0.01015873f);
                t = fmaf(t, u, 0.02857143f);
                t = fmaf(t, u, 0.08888889f);
                t = fmaf(t, u, 0.33333333f);
                t = fmaf(t, u, 2.0f);
                float wv = __expf(-u * t);
                den[reg] += wv;
                Pnx[(quad * 4 + reg) * 72 + nt * 16 + l] = f2bf_trunc(wv);
            }
    }

    // epilogue: PV(7)
    {
        short* Pc = &Ps[w][1][0];
        const short* pr = Pc + l * 72 + quad * 8;
        short8 pa0 = *(const short8*)(pr);
        short8 pa1 = *(const short8*)(pr + 32);
        const short* vj = vtB + 7 * 64;
        #pragma unroll
        for (int nt = 0; nt < 4; ++nt) {
            const short* q = vj + (size_t)(nt * 16 + l) * 2048 + quad * 8;
            short8 b0 = *(const short8*)(q);
            short8 b1 = *(const short8*)(q + 32);
            acc[nt] = MFMA(pa0, b0, acc[nt]);
            acc[nt] = MFMA(pa1, b1, acc[nt]);
        }
    }

    // den: reduce over the 16 l-lanes of each quad; publish per wave
    #pragma unroll
    for (int reg = 0; reg < 4; ++reg) {
        float sm = den[reg];
        #pragma unroll
        for (int msk = 1; msk < 16; msk <<= 1) sm += __shfl_xor(sm, msk);
        if (l == 0) denB[w][quad * 4 + reg] = sm;
    }
    __syncthreads();                       // all waves done with Ps + denB ready

    // fp32 combine reusing Ps (4 x 1088 floats = 17,408 B <= 18,432 B)
    float* Cb = (float*)&Ps[0][0][0];
    float* Cw = Cb + w * 1088;
    #pragma unroll
    for (int nt = 0; nt < 4; ++nt)
        #pragma unroll
        for (int reg = 0; reg < 4; ++reg)
            Cw[(quad * 4 + reg) * 68 + nt * 16 + l] = acc[nt][reg];
    __syncthreads();

    const int b = bh >> 3, hh = bh & 7;
    #pragma unroll
    for (int reg = 0; reg < 4; ++reg) {
        const int row = quad * 4 + reg;
        float num = 0.f, dt = 0.f;
        #pragma unroll
        for (int s2 = 0; s2 < 4; ++s2) {
            num += Cb[s2 * 1088 + row * 68 + w * 16 + l];
            dt  += denB[s2][row];
        }
        attB[((size_t)(b * 2048 + m0 + row)) * 512 + hh * 64 + w * 16 + l] =
            f2bf(num / dt);
    }
}

// ---------------------------------------------------------------------------
// Kernel 3: out = attB[4096][512](bf16) @ Wo + bo -> fp32 [4096][1024]
// 128-thr blocks = 2 waves; wave = 64x64 tile. Grid (16, 32).
// ---------------------------------------------------------------------------
__global__ __launch_bounds__(128) void out_mfma(
    const short* __restrict__ attB, const short* __restrict__ wot,
    const float* __restrict__ bo, float* __restrict__ out)
{
    const int n0 = blockIdx.x << 6;
    const int tid = threadIdx.x;
    const int w = tid >> 6, lane = tid & 63;
    const int l = lane & 15, quad = lane >> 4;
    const int m0 = blockIdx.y * 128 + w * 64;

    const short* ap[4];
    const short* bp[4];
    #pragma unroll
    for (int i = 0; i < 4; ++i)
        ap[i] = attB + (size_t)(m0 + i * 16 + l) * 512 + quad * 8;
    #pragma unroll
    for (int j = 0; j < 4; ++j)
        bp[j] = wot + (size_t)(n0 + j * 16 + l) * 512 + quad * 8;

    const f32x4 z4 = {0.f, 0.f, 0.f, 0.f};
    f32x4 acc[4][4];
    #pragma unroll
    for (int i = 0; i < 4; ++i)
        #pragma unroll
        for (int j = 0; j < 4; ++j) acc[i][j] = z4;

    short8 Af[4], Bf[4], Ag[4], Bg[4];
    #pragma unroll
    for (int i = 0; i < 4; ++i) { Af[i] = *(const short8*)ap[i]; Bf[i] = *(const short8*)bp[i]; }

    #pragma unroll 1
    for (int kc = 0; kc < 16; kc += 2) {
        const int ko1 = (kc + 1) * 32;
        #pragma unroll
        for (int i = 0; i < 4; ++i) {
            Ag[i] = *(const short8*)(ap[i] + ko1);
            Bg[i] = *(const short8*)(bp[i] + ko1);
        }
        #pragma unroll
        for (int i = 0; i < 4; ++i)
            #pragma unroll
            for (int j = 0; j < 4; ++j)
                acc[i][j] = MFMA(Af[i], Bf[j], acc[i][j]);
        const int ko2 = (kc + 2 < 16) ? (kc + 2) * 32 : 0;   // wrap: harmless
        #pragma unroll
        for (int i = 0; i < 4; ++i) {
            Af[i] = *(const short8*)(ap[i] + ko2);
            Bf[i] = *(const short8*)(bp[i] + ko2);
        }
        #pragma unroll
        for (int i = 0; i < 4; ++i)
            #pragma unroll
            for (int j = 0; j < 4; ++j)
                acc[i][j] = MFMA(Ag[i], Bg[j], acc[i][j]);
    }

    #pragma unroll
    for (int i = 0; i < 4; ++i)
        #pragma unroll
        for (int reg = 0; reg < 4; ++reg) {
            const int m = m0 + i * 16 + quad * 4 + reg;
            float* o = out + (size_t)m * 1024 + n0 + l;
            #pragma unroll
            for (int nt = 0; nt < 4; ++nt)
                o[nt * 16] = acc[i][nt][reg] + bo[n0 + nt * 16 + l];
        }
}

// ---------------------------------------------------------------------------
extern "C" void kernel_launch(void* const* d_in, const int* in_sizes, int n_in,
                              void* d_out, int out_size, void* d_ws, size_t ws_size,
                              hipStream_t stream) {
    const float* xr = (const float*)d_in[0];
    const float* xi = (const float*)d_in[1];
    const float* Wq = (const float*)d_in[2];
    const float* bq = (const float*)d_in[3];
    const float* Wk = (const float*)d_in[4];
    const float* bk = (const float*)d_in[5];
    const float* Wv = (const float*)d_in[6];
    const float* bv = (const float*)d_in[7];
    const float* Wo = (const float*)d_in[8];
    const float* bo = (const float*)d_in[9];
    float* out = (float*)d_out;

    short* base = (short*)d_ws;
    short* xb   = base;                      // 4096*1024
    short* wqt  = xb  + 4194304;             // 512*1024
    short* wkt  = wqt + 524288;
    short* wvt  = wkt + 524288;
    short* wot  = wvt + 524288;              // 1024*512
    short* spW  = wot + 524288;              // 16*2048*64
    short* sqW  = spW + 2097152;
    short* vtW  = sqW + 2097152;             // [b,h,d,s]
    short* attB = vtW + 2097152;             // 4096*512
    // total = 14,680,064 shorts = 28 MB

    hipLaunchKernelGGL(convert_x, dim3(4096), dim3(256), 0, stream, xr, xi, xb);
    hipLaunchKernelGGL(transpose_w, dim3(32, 32, 4), dim3(256), 0, stream,
                       Wq, Wk, Wv, Wo, wqt, wkt, wvt, wot);
    hipLaunchKernelGGL(qkv_mfma, dim3(24, 32), dim3(128), 0, stream,
                       xb, wqt, wkt, wvt, bq, bk, bv, spW, sqW, vtW);
    hipLaunchKernelGGL(attn_mfma, dim3(128, 16), dim3(256), 0, stream,
                       spW, sqW, vtW, attB);
    hipLaunchKernelGGL(out_mfma, dim3(16, 32), dim3(128), 0, stream,
                       attB, wot, bo, out);
}

// Round 8
// 239.591 us; speedup vs baseline: 1.2178x; 1.2178x over previous
//
#include <hip/hip_runtime.h>
#include <math.h>

// GeoAttention on gfx950: B=2, S=2048, DIM=512, H=8, HD=64.
// bf16 MFMA (16x16x32) everywhere, fp32 accumulate.
// R7: attn waves cover 64 Q-rows (4 strips) x 512-j quarter — 64 MFMAs per
// 16-load batch; traffic 256 MB at the measured ~7 TB/s effective load BW.
// (R6's 16-row waves doubled traffic -> 133 us; R4/R5 data fit BW model.)

typedef __attribute__((ext_vector_type(8))) short short8;
typedef __attribute__((ext_vector_type(4))) float f32x4;

#define MFMA(a, b, c) __builtin_amdgcn_mfma_f32_16x16x32_bf16((a), (b), (c), 0, 0, 0)

static __device__ __forceinline__ short f2bf(float f) {
    unsigned u = __float_as_uint(f);
    u += 0x7fffu + ((u >> 16) & 1u);          // round-to-nearest-even
    return (short)(u >> 16);
}
static __device__ __forceinline__ short f2bf_trunc(float f) {
    return (short)(__float_as_uint(f) >> 16); // bias cancels in num/den ratio
}

// ---------------------------------------------------------------------------
// Prep 1: xb[4096][1024] bf16 = concat(x_real, x_imag)
// ---------------------------------------------------------------------------
__global__ __launch_bounds__(256) void convert_x(
    const float* __restrict__ xr, const float* __restrict__ xi,
    short* __restrict__ xb)
{
    int idx = blockIdx.x * 256 + threadIdx.x;
    int e = idx << 2;
    int m = e >> 10, k = e & 1023;
    const float* src = (k < 512) ? xr : xi;
    float4 t = *(const float4*)(src + (size_t)m * 512 + (k & 511));
    unsigned lo = (unsigned short)f2bf(t.x) | ((unsigned)(unsigned short)f2bf(t.y) << 16);
    unsigned hi = (unsigned short)f2bf(t.z) | ((unsigned)(unsigned short)f2bf(t.w) << 16);
    uint2 o; o.x = lo; o.y = hi;
    *(uint2*)(xb + e) = o;
}

// ---------------------------------------------------------------------------
// Prep 2: transpose + convert weights to bf16, n-major [N][K].
// ---------------------------------------------------------------------------
__global__ __launch_bounds__(256) void transpose_w(
    const float* __restrict__ Wq, const float* __restrict__ Wk,
    const float* __restrict__ Wv, const float* __restrict__ Wo,
    short* __restrict__ wqt, short* __restrict__ wkt,
    short* __restrict__ wvt, short* __restrict__ wot)
{
    __shared__ float t[32][33];
    const int z = blockIdx.z;
    const float* src = (z == 0) ? Wq : (z == 1) ? Wk : (z == 2) ? Wv : Wo;
    short* dst = (z == 0) ? wqt : (z == 1) ? wkt : (z == 2) ? wvt : wot;
    const int K = (z < 3) ? 1024 : 512;
    const int N = (z < 3) ? 512 : 1024;
    const int n0 = blockIdx.x << 5, k0 = blockIdx.y << 5;
    if (n0 >= N || k0 >= K) return;
    const int tx = threadIdx.x & 31, ty = threadIdx.x >> 5;
    #pragma unroll
    for (int i = 0; i < 4; ++i)
        t[ty + 8 * i][tx] = src[(size_t)(k0 + ty + 8 * i) * N + n0 + tx];
    __syncthreads();
    #pragma unroll
    for (int i = 0; i < 4; ++i)
        dst[(size_t)(n0 + ty + 8 * i) * K + k0 + tx] = f2bf(t[tx][ty + 8 * i]);
}

// ---------------------------------------------------------------------------
// Kernel 1: QKV projection + fused softmax(64)+sqrt epilogue.
// 128-thr blocks = 2 waves; wave = 64 rows x 64 cols (16 MFMA per 8 loads).
// ---------------------------------------------------------------------------
__global__ __launch_bounds__(128) void qkv_mfma(
    const short* __restrict__ xb,
    const short* __restrict__ wqt, const short* __restrict__ wkt,
    const short* __restrict__ wvt,
    const float* __restrict__ bq, const float* __restrict__ bk,
    const float* __restrict__ bv,
    short* __restrict__ sp, short* __restrict__ sq, short* __restrict__ vt)
{
    __shared__ short vbuf[2][64 * 72];        // per-wave [d=64][s=64 +pad8]
    const int iwb = blockIdx.x;
    const int iw = iwb >> 3;
    const int h  = iwb & 7;
    const int tid = threadIdx.x;
    const int w = tid >> 6, lane = tid & 63;
    const int l = lane & 15, quad = lane >> 4;
    const int m0 = blockIdx.y * 128 + w * 64;

    const short* wt   = (iw == 0) ? wqt : (iw == 1) ? wkt : wvt;
    const float* bias = (iw == 0) ? bq  : (iw == 1) ? bk  : bv;
    short* dst        = (iw == 0) ? sp  : (iw == 1) ? sq  : vt;

    const short* ap[4];
    const short* bp[4];
    #pragma unroll
    for (int i = 0; i < 4; ++i)
        ap[i] = xb + (size_t)(m0 + i * 16 + l) * 1024 + quad * 8;
    #pragma unroll
    for (int j = 0; j < 4; ++j)
        bp[j] = wt + (size_t)(h * 64 + j * 16 + l) * 1024 + quad * 8;

    const f32x4 z4 = {0.f, 0.f, 0.f, 0.f};
    f32x4 acc[4][4];
    #pragma unroll
    for (int i = 0; i < 4; ++i)
        #pragma unroll
        for (int j = 0; j < 4; ++j) acc[i][j] = z4;

    short8 Af[4], Bf[4], Ag[4], Bg[4];
    #pragma unroll
    for (int i = 0; i < 4; ++i) { Af[i] = *(const short8*)ap[i]; Bf[i] = *(const short8*)bp[i]; }

    #pragma unroll 1
    for (int kc = 0; kc < 32; kc += 2) {
        const int ko1 = (kc + 1) * 32;
        #pragma unroll
        for (int i = 0; i < 4; ++i) {
            Ag[i] = *(const short8*)(ap[i] + ko1);
            Bg[i] = *(const short8*)(bp[i] + ko1);
        }
        #pragma unroll
        for (int i = 0; i < 4; ++i)
            #pragma unroll
            for (int j = 0; j < 4; ++j)
                acc[i][j] = MFMA(Af[i], Bf[j], acc[i][j]);
        const int ko2 = (kc + 2 < 32) ? (kc + 2) * 32 : 0;   // wrap: harmless
        #pragma unroll
        for (int i = 0; i < 4; ++i) {
            Af[i] = *(const short8*)(ap[i] + ko2);
            Bf[i] = *(const short8*)(bp[i] + ko2);
        }
        #pragma unroll
        for (int i = 0; i < 4; ++i)
            #pragma unroll
            for (int j = 0; j < 4; ++j)
                acc[i][j] = MFMA(Ag[i], Bg[j], acc[i][j]);
    }

    float bcol[4];
    #pragma unroll
    for (int nt = 0; nt < 4; ++nt) bcol[nt] = bias[h * 64 + nt * 16 + l];

    #pragma unroll
    for (int i = 0; i < 4; ++i) {
        #pragma unroll
        for (int reg = 0; reg < 4; ++reg) {
            const int sg = m0 + i * 16 + quad * 4 + reg;     // global row
            const int b = sg >> 11, s = sg & 2047;
            float v[4];
            #pragma unroll
            for (int nt = 0; nt < 4; ++nt) v[nt] = acc[i][nt][reg] + bcol[nt];
            if (iw < 2) {
                float mx = fmaxf(fmaxf(v[0], v[1]), fmaxf(v[2], v[3]));
                #pragma unroll
                for (int msk = 1; msk < 16; msk <<= 1) mx = fmaxf(mx, __shfl_xor(mx, msk));
                float e[4], ssum = 0.f;
                #pragma unroll
                for (int nt = 0; nt < 4; ++nt) { e[nt] = __expf(v[nt] - mx); ssum += e[nt]; }
                #pragma unroll
                for (int msk = 1; msk < 16; msk <<= 1) ssum += __shfl_xor(ssum, msk);
                float inv = 1.0f / ssum;
                short* o = dst + ((size_t)(b * 8 + h) * 2048 + s) * 64 + l;
                #pragma unroll
                for (int nt = 0; nt < 4; ++nt)
                    o[nt * 16] = f2bf(sqrtf(e[nt] * inv));
            } else {
                const int sl = i * 16 + quad * 4 + reg;      // local s in [0,64)
                #pragma unroll
                for (int nt = 0; nt < 4; ++nt)
                    vbuf[w][(nt * 16 + l) * 72 + sl] = f2bf(v[nt]);
            }
        }
    }

    if (iw == 2) {
        const int d = lane;
        const short* row = &vbuf[w][d * 72];
        const int b = m0 >> 11, s0 = m0 & 2047;
        short* gp = vt + ((size_t)(b * 8 + h) * 64 + d) * 2048 + s0;
        #pragma unroll
        for (int r = 0; r < 8; ++r)
            *(short8*)(gp + r * 8) = *(const short8*)(row + r * 8);
    }
}

// ---------------------------------------------------------------------------
// Kernel 2: attention. Grid (32, 16), 256 threads = 4 waves.
// Block = 64 Q-rows; wave w = j-quarter (512 j, 8 jt of 64), 4 row-strips.
// Per jt: QK(4 strips) + transform immediately; sq-prefetch after last use;
// P via wave-private LDS (single buffer, same-iter write->read); PV with
// inline V loads. Epilogue: 4 strip-phases of fp32 combine reusing Ps.
// ---------------------------------------------------------------------------
__global__ __launch_bounds__(256) void attn_mfma(
    const short* __restrict__ sp, const short* __restrict__ sq,
    const short* __restrict__ vt, short* __restrict__ attB)
{
    __shared__ short Ps[4][64 * 72];            // 36,864 B bf16 P (fp32 reuse)
    __shared__ float denB[4][64];               // 1 KB
    const int bh = blockIdx.y;
    const int m0 = blockIdx.x << 6;             // 64 Q-rows per block
    const int tid = threadIdx.x;
    const int w = tid >> 6, lane = tid & 63;
    const int l = lane & 15, quad = lane >> 4;

    const short* spB = sp + (size_t)bh * 2048 * 64;
    const short* sqB = sq + (size_t)bh * 2048 * 64 + (size_t)(w * 512) * 64;
    const short* vtB = vt + (size_t)bh * 64 * 2048 + w * 512;
    short* P = &Ps[w][0];

    // A frags: 4 strips of 16 rows
    short8 aq[4][2];
    #pragma unroll
    for (int s = 0; s < 4; ++s) {
        const short* apr = spB + (size_t)(m0 + s * 16 + l) * 64 + quad * 8;
        aq[s][0] = *(const short8*)(apr);
        aq[s][1] = *(const short8*)(apr + 32);
    }

    const f32x4 z4 = {0.f, 0.f, 0.f, 0.f};
    f32x4 acc[4][4];                            // [strip][nt]
    float den[4][4];                            // [strip][reg]
    #pragma unroll
    for (int s = 0; s < 4; ++s)
        #pragma unroll
        for (int j = 0; j < 4; ++j) { acc[s][j] = z4; den[s][j] = 0.f; }

    // preload sq frags for jt=0
    short8 sqb[4][2];
    #pragma unroll
    for (int nt = 0; nt < 4; ++nt) {
        const short* q = sqB + (size_t)(nt * 16 + l) * 64 + quad * 8;
        sqb[nt][0] = *(const short8*)(q);
        sqb[nt][1] = *(const short8*)(q + 32);
    }

    #pragma unroll 1
    for (int jt = 0; jt < 8; ++jt) {
        // QK^T + transform, strip-major inside nt
        #pragma unroll
        for (int nt = 0; nt < 4; ++nt) {
            #pragma unroll
            for (int s = 0; s < 4; ++s) {
                f32x4 p = MFMA(aq[s][0], sqb[nt][0], z4);
                p = MFMA(aq[s][1], sqb[nt][1], p);
                #pragma unroll
                for (int reg = 0; reg < 4; ++reg) {
                    // bc in [0,1]; acos(x)^2 = 2u + u^2/3 + ..., u = 1-x
                    float u = fmaxf(1.0f - p[reg], 0.0f);
                    float t = 0.000922f;
                    t = fmaf(t, u, 0.00152228f);
                    t = fmaf(t, u, 0.00384801f);
                    t = fmaf(t, u, 0.01015873f);
                    t = fmaf(t, u, 0.02857143f);
                    t = fmaf(t, u, 0.08888889f);
                    t = fmaf(t, u, 0.33333333f);
                    t = fmaf(t, u, 2.0f);
                    float wv = __expf(-u * t);
                    den[s][reg] += wv;
                    P[(s * 16 + quad * 4 + reg) * 72 + nt * 16 + l] = f2bf_trunc(wv);
                }
            }
        }
        // prefetch sq(jt+1) — sqb dead now (wrap: harmless re-read)
        const short* sqn = sqB + (size_t)(((jt + 1) & 7) * 64) * 64;
        #pragma unroll
        for (int nt = 0; nt < 4; ++nt) {
            const short* q = sqn + (size_t)(nt * 16 + l) * 64 + quad * 8;
            sqb[nt][0] = *(const short8*)(q);
            sqb[nt][1] = *(const short8*)(q + 32);
        }
        // P rows -> A-frags (stride-72 rows: 144B, 16B-aligned)
        short8 pa[4][2];
        #pragma unroll
        for (int s = 0; s < 4; ++s) {
            const short* pr = P + (s * 16 + l) * 72 + quad * 8;
            pa[s][0] = *(const short8*)(pr);
            pa[s][1] = *(const short8*)(pr + 32);
        }
        // PV with inline V loads (vt slice L2-hot: shared by 32 blocks)
        const short* vj = vtB + jt * 64;
        #pragma unroll
        for (int nt = 0; nt < 4; ++nt) {
            const short* q = vj + (size_t)(nt * 16 + l) * 2048 + quad * 8;
            short8 b0 = *(const short8*)(q);
            short8 b1 = *(const short8*)(q + 32);
            #pragma unroll
            for (int s = 0; s < 4; ++s) {
                acc[s][nt] = MFMA(pa[s][0], b0, acc[s][nt]);
                acc[s][nt] = MFMA(pa[s][1], b1, acc[s][nt]);
            }
        }
    }

    // den: reduce over the 16 l-lanes of each quad; publish per wave
    #pragma unroll
    for (int s = 0; s < 4; ++s)
        #pragma unroll
        for (int reg = 0; reg < 4; ++reg) {
            float sm = den[s][reg];
            #pragma unroll
            for (int msk = 1; msk < 16; msk <<= 1) sm += __shfl_xor(sm, msk);
            if (l == 0) denB[w][s * 16 + quad * 4 + reg] = sm;
        }
    __syncthreads();

    // 4 strip-phases of fp32 combine reusing Ps (4 x 1088 floats = 17.4 KB)
    float* Cb = (float*)&Ps[0][0];
    const int b = bh >> 3, hh = bh & 7;
    #pragma unroll
    for (int ph = 0; ph < 4; ++ph) {
        float* Cw = Cb + w * 1088;
        #pragma unroll
        for (int nt = 0; nt < 4; ++nt)
            #pragma unroll
            for (int reg = 0; reg < 4; ++reg)
                Cw[(quad * 4 + reg) * 68 + nt * 16 + l] = acc[ph][nt][reg];
        __syncthreads();
        #pragma unroll
        for (int reg = 0; reg < 4; ++reg) {
            const int r16 = quad * 4 + reg;
            float num = 0.f, dt = 0.f;
            #pragma unroll
            for (int s2 = 0; s2 < 4; ++s2) {
                num += Cb[s2 * 1088 + r16 * 68 + w * 16 + l];
                dt  += denB[s2][ph * 16 + r16];
            }
            const int srow = m0 + ph * 16 + r16;
            attB[((size_t)(b * 2048 + srow)) * 512 + hh * 64 + w * 16 + l] =
                f2bf(num / dt);
        }
        __syncthreads();
    }
}

// ---------------------------------------------------------------------------
// Kernel 3: out = attB[4096][512](bf16) @ Wo + bo -> fp32 [4096][1024]
// 128-thr blocks = 2 waves; wave = 64x64 tile. Grid (16, 32).
// ---------------------------------------------------------------------------
__global__ __launch_bounds__(128) void out_mfma(
    const short* __restrict__ attB, const short* __restrict__ wot,
    const float* __restrict__ bo, float* __restrict__ out)
{
    const int n0 = blockIdx.x << 6;
    const int tid = threadIdx.x;
    const int w = tid >> 6, lane = tid & 63;
    const int l = lane & 15, quad = lane >> 4;
    const int m0 = blockIdx.y * 128 + w * 64;

    const short* ap[4];
    const short* bp[4];
    #pragma unroll
    for (int i = 0; i < 4; ++i)
        ap[i] = attB + (size_t)(m0 + i * 16 + l) * 512 + quad * 8;
    #pragma unroll
    for (int j = 0; j < 4; ++j)
        bp[j] = wot + (size_t)(n0 + j * 16 + l) * 512 + quad * 8;

    const f32x4 z4 = {0.f, 0.f, 0.f, 0.f};
    f32x4 acc[4][4];
    #pragma unroll
    for (int i = 0; i < 4; ++i)
        #pragma unroll
        for (int j = 0; j < 4; ++j) acc[i][j] = z4;

    short8 Af[4], Bf[4], Ag[4], Bg[4];
    #pragma unroll
    for (int i = 0; i < 4; ++i) { Af[i] = *(const short8*)ap[i]; Bf[i] = *(const short8*)bp[i]; }

    #pragma unroll 1
    for (int kc = 0; kc < 16; kc += 2) {
        const int ko1 = (kc + 1) * 32;
        #pragma unroll
        for (int i = 0; i < 4; ++i) {
            Ag[i] = *(const short8*)(ap[i] + ko1);
            Bg[i] = *(const short8*)(bp[i] + ko1);
        }
        #pragma unroll
        for (int i = 0; i < 4; ++i)
            #pragma unroll
            for (int j = 0; j < 4; ++j)
                acc[i][j] = MFMA(Af[i], Bf[j], acc[i][j]);
        const int ko2 = (kc + 2 < 16) ? (kc + 2) * 32 : 0;   // wrap: harmless
        #pragma unroll
        for (int i = 0; i < 4; ++i) {
            Af[i] = *(const short8*)(ap[i] + ko2);
            Bf[i] = *(const short8*)(bp[i] + ko2);
        }
        #pragma unroll
        for (int i = 0; i < 4; ++i)
            #pragma unroll
            for (int j = 0; j < 4; ++j)
                acc[i][j] = MFMA(Ag[i], Bg[j], acc[i][j]);
    }

    #pragma unroll
    for (int i = 0; i < 4; ++i)
        #pragma unroll
        for (int reg = 0; reg < 4; ++reg) {
            const int m = m0 + i * 16 + quad * 4 + reg;
            float* o = out + (size_t)m * 1024 + n0 + l;
            #pragma unroll
            for (int nt = 0; nt < 4; ++nt)
                o[nt * 16] = acc[i][nt][reg] + bo[n0 + nt * 16 + l];
        }
}

// ---------------------------------------------------------------------------
extern "C" void kernel_launch(void* const* d_in, const int* in_sizes, int n_in,
                              void* d_out, int out_size, void* d_ws, size_t ws_size,
                              hipStream_t stream) {
    const float* xr = (const float*)d_in[0];
    const float* xi = (const float*)d_in[1];
    const float* Wq = (const float*)d_in[2];
    const float* bq = (const float*)d_in[3];
    const float* Wk = (const float*)d_in[4];
    const float* bk = (const float*)d_in[5];
    const float* Wv = (const float*)d_in[6];
    const float* bv = (const float*)d_in[7];
    const float* Wo = (const float*)d_in[8];
    const float* bo = (const float*)d_in[9];
    float* out = (float*)d_out;

    short* base = (short*)d_ws;
    short* xb   = base;                      // 4096*1024
    short* wqt  = xb  + 4194304;             // 512*1024
    short* wkt  = wqt + 524288;
    short* wvt  = wkt + 524288;
    short* wot  = wvt + 524288;              // 1024*512
    short* spW  = wot + 524288;              // 16*2048*64
    short* sqW  = spW + 2097152;
    short* vtW  = sqW + 2097152;             // [b,h,d,s]
    short* attB = vtW + 2097152;             // 4096*512
    // total = 14,680,064 shorts = 28 MB

    hipLaunchKernelGGL(convert_x, dim3(4096), dim3(256), 0, stream, xr, xi, xb);
    hipLaunchKernelGGL(transpose_w, dim3(32, 32, 4), dim3(256), 0, stream,
                       Wq, Wk, Wv, Wo, wqt, wkt, wvt, wot);
    hipLaunchKernelGGL(qkv_mfma, dim3(24, 32), dim3(128), 0, stream,
                       xb, wqt, wkt, wvt, bq, bk, bv, spW, sqW, vtW);
    hipLaunchKernelGGL(attn_mfma, dim3(32, 16), dim3(256), 0, stream,
                       spW, sqW, vtW, attB);
    hipLaunchKernelGGL(out_mfma, dim3(16, 32), dim3(128), 0, stream,
                       attB, wot, bo, out);
}

// Round 9
// 213.666 us; speedup vs baseline: 1.3656x; 1.1213x over previous
//
#include <hip/hip_runtime.h>
#include <math.h>

// GeoAttention on gfx950: B=2, S=2048, DIM=512, H=8, HD=64.
// bf16 MFMA (16x16x32) everywhere, fp32 accumulate.
// R8: attn rebuilt m97-style — block-cooperative double-buffered LDS tiles
// (sq 8KB + vt 8KB per jt, stride-72 rows, 1 barrier/jt), QK computed
// TRANSPOSED so lane = Q-row (P packs as b64, den is per-lane scalar, no
// cross-wave combine). VGPR ~90 -> 4 waves/SIMD (R7's 172 VGPR = 2/SIMD,
// 10.7% occupancy was the latency wall).

typedef __attribute__((ext_vector_type(8))) short short8;
typedef __attribute__((ext_vector_type(4))) float f32x4;

#define MFMA(a, b, c) __builtin_amdgcn_mfma_f32_16x16x32_bf16((a), (b), (c), 0, 0, 0)

static __device__ __forceinline__ short f2bf(float f) {
    unsigned u = __float_as_uint(f);
    u += 0x7fffu + ((u >> 16) & 1u);          // round-to-nearest-even
    return (short)(u >> 16);
}

// ---------------------------------------------------------------------------
// Prep 1: xb[4096][1024] bf16 = concat(x_real, x_imag)
// ---------------------------------------------------------------------------
__global__ __launch_bounds__(256) void convert_x(
    const float* __restrict__ xr, const float* __restrict__ xi,
    short* __restrict__ xb)
{
    int idx = blockIdx.x * 256 + threadIdx.x;
    int e = idx << 2;
    int m = e >> 10, k = e & 1023;
    const float* src = (k < 512) ? xr : xi;
    float4 t = *(const float4*)(src + (size_t)m * 512 + (k & 511));
    unsigned lo = (unsigned short)f2bf(t.x) | ((unsigned)(unsigned short)f2bf(t.y) << 16);
    unsigned hi = (unsigned short)f2bf(t.z) | ((unsigned)(unsigned short)f2bf(t.w) << 16);
    uint2 o; o.x = lo; o.y = hi;
    *(uint2*)(xb + e) = o;
}

// ---------------------------------------------------------------------------
// Prep 2: transpose + convert weights to bf16, n-major [N][K].
// ---------------------------------------------------------------------------
__global__ __launch_bounds__(256) void transpose_w(
    const float* __restrict__ Wq, const float* __restrict__ Wk,
    const float* __restrict__ Wv, const float* __restrict__ Wo,
    short* __restrict__ wqt, short* __restrict__ wkt,
    short* __restrict__ wvt, short* __restrict__ wot)
{
    __shared__ float t[32][33];
    const int z = blockIdx.z;
    const float* src = (z == 0) ? Wq : (z == 1) ? Wk : (z == 2) ? Wv : Wo;
    short* dst = (z == 0) ? wqt : (z == 1) ? wkt : (z == 2) ? wvt : wot;
    const int K = (z < 3) ? 1024 : 512;
    const int N = (z < 3) ? 512 : 1024;
    const int n0 = blockIdx.x << 5, k0 = blockIdx.y << 5;
    if (n0 >= N || k0 >= K) return;
    const int tx = threadIdx.x & 31, ty = threadIdx.x >> 5;
    #pragma unroll
    for (int i = 0; i < 4; ++i)
        t[ty + 8 * i][tx] = src[(size_t)(k0 + ty + 8 * i) * N + n0 + tx];
    __syncthreads();
    #pragma unroll
    for (int i = 0; i < 4; ++i)
        dst[(size_t)(n0 + ty + 8 * i) * K + k0 + tx] = f2bf(t[tx][ty + 8 * i]);
}

// ---------------------------------------------------------------------------
// Kernel 1: QKV projection + fused softmax(64)+sqrt epilogue. (unchanged R7)
// ---------------------------------------------------------------------------
__global__ __launch_bounds__(128) void qkv_mfma(
    const short* __restrict__ xb,
    const short* __restrict__ wqt, const short* __restrict__ wkt,
    const short* __restrict__ wvt,
    const float* __restrict__ bq, const float* __restrict__ bk,
    const float* __restrict__ bv,
    short* __restrict__ sp, short* __restrict__ sq, short* __restrict__ vt)
{
    __shared__ short vbuf[2][64 * 72];        // per-wave [d=64][s=64 +pad8]
    const int iwb = blockIdx.x;
    const int iw = iwb >> 3;
    const int h  = iwb & 7;
    const int tid = threadIdx.x;
    const int w = tid >> 6, lane = tid & 63;
    const int l = lane & 15, quad = lane >> 4;
    const int m0 = blockIdx.y * 128 + w * 64;

    const short* wt   = (iw == 0) ? wqt : (iw == 1) ? wkt : wvt;
    const float* bias = (iw == 0) ? bq  : (iw == 1) ? bk  : bv;
    short* dst        = (iw == 0) ? sp  : (iw == 1) ? sq  : vt;

    const short* ap[4];
    const short* bp[4];
    #pragma unroll
    for (int i = 0; i < 4; ++i)
        ap[i] = xb + (size_t)(m0 + i * 16 + l) * 1024 + quad * 8;
    #pragma unroll
    for (int j = 0; j < 4; ++j)
        bp[j] = wt + (size_t)(h * 64 + j * 16 + l) * 1024 + quad * 8;

    const f32x4 z4 = {0.f, 0.f, 0.f, 0.f};
    f32x4 acc[4][4];
    #pragma unroll
    for (int i = 0; i < 4; ++i)
        #pragma unroll
        for (int j = 0; j < 4; ++j) acc[i][j] = z4;

    short8 Af[4], Bf[4], Ag[4], Bg[4];
    #pragma unroll
    for (int i = 0; i < 4; ++i) { Af[i] = *(const short8*)ap[i]; Bf[i] = *(const short8*)bp[i]; }

    #pragma unroll 1
    for (int kc = 0; kc < 32; kc += 2) {
        const int ko1 = (kc + 1) * 32;
        #pragma unroll
        for (int i = 0; i < 4; ++i) {
            Ag[i] = *(const short8*)(ap[i] + ko1);
            Bg[i] = *(const short8*)(bp[i] + ko1);
        }
        #pragma unroll
        for (int i = 0; i < 4; ++i)
            #pragma unroll
            for (int j = 0; j < 4; ++j)
                acc[i][j] = MFMA(Af[i], Bf[j], acc[i][j]);
        const int ko2 = (kc + 2 < 32) ? (kc + 2) * 32 : 0;   // wrap: harmless
        #pragma unroll
        for (int i = 0; i < 4; ++i) {
            Af[i] = *(const short8*)(ap[i] + ko2);
            Bf[i] = *(const short8*)(bp[i] + ko2);
        }
        #pragma unroll
        for (int i = 0; i < 4; ++i)
            #pragma unroll
            for (int j = 0; j < 4; ++j)
                acc[i][j] = MFMA(Ag[i], Bg[j], acc[i][j]);
    }

    float bcol[4];
    #pragma unroll
    for (int nt = 0; nt < 4; ++nt) bcol[nt] = bias[h * 64 + nt * 16 + l];

    #pragma unroll
    for (int i = 0; i < 4; ++i) {
        #pragma unroll
        for (int reg = 0; reg < 4; ++reg) {
            const int sg = m0 + i * 16 + quad * 4 + reg;     // global row
            const int b = sg >> 11, s = sg & 2047;
            float v[4];
            #pragma unroll
            for (int nt = 0; nt < 4; ++nt) v[nt] = acc[i][nt][reg] + bcol[nt];
            if (iw < 2) {
                float mx = fmaxf(fmaxf(v[0], v[1]), fmaxf(v[2], v[3]));
                #pragma unroll
                for (int msk = 1; msk < 16; msk <<= 1) mx = fmaxf(mx, __shfl_xor(mx, msk));
                float e[4], ssum = 0.f;
                #pragma unroll
                for (int nt = 0; nt < 4; ++nt) { e[nt] = __expf(v[nt] - mx); ssum += e[nt]; }
                #pragma unroll
                for (int msk = 1; msk < 16; msk <<= 1) ssum += __shfl_xor(ssum, msk);
                float inv = 1.0f / ssum;
                short* o = dst + ((size_t)(b * 8 + h) * 2048 + s) * 64 + l;
                #pragma unroll
                for (int nt = 0; nt < 4; ++nt)
                    o[nt * 16] = f2bf(sqrtf(e[nt] * inv));
            } else {
                const int sl = i * 16 + quad * 4 + reg;      // local s in [0,64)
                #pragma unroll
                for (int nt = 0; nt < 4; ++nt)
                    vbuf[w][(nt * 16 + l) * 72 + sl] = f2bf(v[nt]);
            }
        }
    }

    if (iw == 2) {
        const int d = lane;
        const short* row = &vbuf[w][d * 72];
        const int b = m0 >> 11, s0 = m0 & 2047;
        short* gp = vt + ((size_t)(b * 8 + h) * 64 + d) * 2048 + s0;
        #pragma unroll
        for (int r = 0; r < 8; ++r)
            *(short8*)(gp + r * 8) = *(const short8*)(row + r * 8);
    }
}

// ---------------------------------------------------------------------------
// Kernel 2: attention. Grid (32, 16), 256 threads = 4 waves.
// Block = 64 Q-rows (wave w -> 16-row strip), full 2048-j sweep in 32 jts.
// Per jt: cooperative stage of sq[64j][64d] + vt[64d][64j] tiles into
// double-buffered LDS (stride-72 rows, 1 barrier). QK computed TRANSPOSED
// (MFMA(sq,sp)) so lane=Q-row: P packs 4 consecutive-j bf16 per b64 write,
// PV reads P rows directly as A-frags, den is a per-lane scalar.
// ---------------------------------------------------------------------------
__global__ __launch_bounds__(256, 4) void attn_mfma(
    const short* __restrict__ sp, const short* __restrict__ sq,
    const short* __restrict__ vt, short* __restrict__ attB)
{
    __shared__ short sqT[2][64 * 72];           // [j][d] staged sq tile
    __shared__ short vtT[2][64 * 72];           // [d][j] staged vt tile
    __shared__ short Pb[4][16 * 72];            // per-wave P [row][j]
    __shared__ float denB[4][16];
    const int bh = blockIdx.y;
    const int m0 = blockIdx.x << 6;
    const int tid = threadIdx.x;
    const int w = tid >> 6, lane = tid & 63;
    const int l = lane & 15, quad = lane >> 4;

    const short* spB = sp + (size_t)bh * 2048 * 64;
    const short* sqB = sq + (size_t)bh * 2048 * 64;
    const short* vtB = vt + (size_t)bh * 64 * 2048;

    // persistent sp frags (B-operand): lane l holds sp row (m0+w*16+l)
    const short* apr = spB + (size_t)(m0 + w * 16 + l) * 64 + quad * 8;
    short8 aq0 = *(const short8*)(apr);
    short8 aq1 = *(const short8*)(apr + 32);

    // staging assignment: thread -> tile row (tid>>2), 16-short col (tid&3)*16
    const int srow = tid >> 2;
    const int scol = (tid & 3) * 16;
    const short* sqG = sqB + (size_t)srow * 64 + scol;   // + j0*64 per jt
    const short* vtG = vtB + (size_t)srow * 2048 + scol; // + j0 per jt (cols j)
    const int ldsOff = srow * 72 + scol;

    // prologue: stage jt=0 into buffer 0
    {
        short8 a0 = *(const short8*)(sqG);
        short8 a1 = *(const short8*)(sqG + 8);
        short8 b0 = *(const short8*)(vtG);
        short8 b1 = *(const short8*)(vtG + 8);
        *(short8*)(&sqT[0][ldsOff])     = a0;
        *(short8*)(&sqT[0][ldsOff + 8]) = a1;
        *(short8*)(&vtT[0][ldsOff])     = b0;
        *(short8*)(&vtT[0][ldsOff + 8]) = b1;
    }
    __syncthreads();

    const f32x4 z4 = {0.f, 0.f, 0.f, 0.f};
    f32x4 acc[4] = {z4, z4, z4, z4};
    float den = 0.f;
    short* Pw = &Pb[w][0];

    #pragma unroll 1
    for (int jt = 0; jt < 32; ++jt) {
        const int cb = jt & 1, nb = cb ^ 1;
        const int j0n = ((jt + 1) & 31) << 6;   // wrap: harmless re-stage
        // global loads for jt+1 (latency covered by compute below)
        short8 na0 = *(const short8*)(sqG + (size_t)j0n * 64);
        short8 na1 = *(const short8*)(sqG + (size_t)j0n * 64 + 8);
        short8 nb0 = *(const short8*)(vtG + j0n);
        short8 nb1 = *(const short8*)(vtG + j0n + 8);

        // QK^T transposed: C[j][r] -> lane l = Q-row, quad*4+reg = j-local
        const short* sqL = &sqT[cb][0];
        #pragma unroll
        for (int nt = 0; nt < 4; ++nt) {
            const short* ar = sqL + (nt * 16 + l) * 72 + quad * 8;
            short8 sa0 = *(const short8*)(ar);
            short8 sa1 = *(const short8*)(ar + 32);
            f32x4 p = MFMA(sa0, aq0, z4);
            p = MFMA(sa1, aq1, p);
            float wv[4];
            #pragma unroll
            for (int reg = 0; reg < 4; ++reg) {
                // bc in [0,1]; acos(x)^2 = 2u + u^2/3 + ..., u = 1-x
                float u = fmaxf(1.0f - p[reg], 0.0f);
                float t = 0.000922f;
                t = fmaf(t, u, 0.00152228f);
                t = fmaf(t, u, 0.00384801f);
                t = fmaf(t, u, 0.01015873f);
                t = fmaf(t, u, 0.02857143f);
                t = fmaf(t, u, 0.08888889f);
                t = fmaf(t, u, 0.33333333f);
                t = fmaf(t, u, 2.0f);
                float e = __expf(-u * t);
                wv[reg] = e;
                den += e;
            }
            // pack 4 consecutive-j bf16 (trunc; bias cancels in num/den)
            uint2 pk;
            pk.x = (__float_as_uint(wv[0]) >> 16) | (__float_as_uint(wv[1]) & 0xffff0000u);
            pk.y = (__float_as_uint(wv[2]) >> 16) | (__float_as_uint(wv[3]) & 0xffff0000u);
            *(uint2*)(&Pw[l * 72 + nt * 16 + quad * 4]) = pk;
        }

        // PV: P rows as A-frags (2 reads feed 8 MFMAs), V B-frags from LDS
        const short* pr = Pw + l * 72 + quad * 8;
        short8 pa0 = *(const short8*)(pr);
        short8 pa1 = *(const short8*)(pr + 32);
        const short* vL = &vtT[cb][0];
        #pragma unroll
        for (int t4 = 0; t4 < 4; ++t4) {
            const short* vr = vL + (t4 * 16 + l) * 72 + quad * 8;
            short8 vb0 = *(const short8*)(vr);
            short8 vb1 = *(const short8*)(vr + 32);
            acc[t4] = MFMA(pa0, vb0, acc[t4]);
            acc[t4] = MFMA(pa1, vb1, acc[t4]);
        }

        // write next tiles into the other buffer, then single barrier
        *(short8*)(&sqT[nb][ldsOff])     = na0;
        *(short8*)(&sqT[nb][ldsOff + 8]) = na1;
        *(short8*)(&vtT[nb][ldsOff])     = nb0;
        *(short8*)(&vtT[nb][ldsOff + 8]) = nb1;
        __syncthreads();
    }

    // den: each quad covered different j -> sum across quads (lane row = l)
    den += __shfl_xor(den, 16);
    den += __shfl_xor(den, 32);
    if (lane < 16) denB[w][l] = den;
    // wave-synchronous LDS: compiler inserts lgkmcnt wait
    float invd[4];
    #pragma unroll
    for (int reg = 0; reg < 4; ++reg)
        invd[reg] = 1.0f / denB[w][quad * 4 + reg];

    const int b = bh >> 3, hh = bh & 7;
    #pragma unroll
    for (int t4 = 0; t4 < 4; ++t4)
        #pragma unroll
        for (int reg = 0; reg < 4; ++reg) {
            const int row = m0 + w * 16 + quad * 4 + reg;
            attB[((size_t)(b * 2048 + row)) * 512 + hh * 64 + t4 * 16 + l] =
                f2bf(acc[t4][reg] * invd[reg]);
        }
}

// ---------------------------------------------------------------------------
// Kernel 3: out = attB[4096][512](bf16) @ Wo + bo -> fp32 (unchanged R7)
// ---------------------------------------------------------------------------
__global__ __launch_bounds__(128) void out_mfma(
    const short* __restrict__ attB, const short* __restrict__ wot,
    const float* __restrict__ bo, float* __restrict__ out)
{
    const int n0 = blockIdx.x << 6;
    const int tid = threadIdx.x;
    const int w = tid >> 6, lane = tid & 63;
    const int l = lane & 15, quad = lane >> 4;
    const int m0 = blockIdx.y * 128 + w * 64;

    const short* ap[4];
    const short* bp[4];
    #pragma unroll
    for (int i = 0; i < 4; ++i)
        ap[i] = attB + (size_t)(m0 + i * 16 + l) * 512 + quad * 8;
    #pragma unroll
    for (int j = 0; j < 4; ++j)
        bp[j] = wot + (size_t)(n0 + j * 16 + l) * 512 + quad * 8;

    const f32x4 z4 = {0.f, 0.f, 0.f, 0.f};
    f32x4 acc[4][4];
    #pragma unroll
    for (int i = 0; i < 4; ++i)
        #pragma unroll
        for (int j = 0; j < 4; ++j) acc[i][j] = z4;

    short8 Af[4], Bf[4], Ag[4], Bg[4];
    #pragma unroll
    for (int i = 0; i < 4; ++i) { Af[i] = *(const short8*)ap[i]; Bf[i] = *(const short8*)bp[i]; }

    #pragma unroll 1
    for (int kc = 0; kc < 16; kc += 2) {
        const int ko1 = (kc + 1) * 32;
        #pragma unroll
        for (int i = 0; i < 4; ++i) {
            Ag[i] = *(const short8*)(ap[i] + ko1);
            Bg[i] = *(const short8*)(bp[i] + ko1);
        }
        #pragma unroll
        for (int i = 0; i < 4; ++i)
            #pragma unroll
            for (int j = 0; j < 4; ++j)
                acc[i][j] = MFMA(Af[i], Bf[j], acc[i][j]);
        const int ko2 = (kc + 2 < 16) ? (kc + 2) * 32 : 0;   // wrap: harmless
        #pragma unroll
        for (int i = 0; i < 4; ++i) {
            Af[i] = *(const short8*)(ap[i] + ko2);
            Bf[i] = *(const short8*)(bp[i] + ko2);
        }
        #pragma unroll
        for (int i = 0; i < 4; ++i)
            #pragma unroll
            for (int j = 0; j < 4; ++j)
                acc[i][j] = MFMA(Ag[i], Bg[j], acc[i][j]);
    }

    #pragma unroll
    for (int i = 0; i < 4; ++i)
        #pragma unroll
        for (int reg = 0; reg < 4; ++reg) {
            const int m = m0 + i * 16 + quad * 4 + reg;
            float* o = out + (size_t)m * 1024 + n0 + l;
            #pragma unroll
            for (int nt = 0; nt < 4; ++nt)
                o[nt * 16] = acc[i][nt][reg] + bo[n0 + nt * 16 + l];
        }
}

// ---------------------------------------------------------------------------
extern "C" void kernel_launch(void* const* d_in, const int* in_sizes, int n_in,
                              void* d_out, int out_size, void* d_ws, size_t ws_size,
                              hipStream_t stream) {
    const float* xr = (const float*)d_in[0];
    const float* xi = (const float*)d_in[1];
    const float* Wq = (const float*)d_in[2];
    const float* bq = (const float*)d_in[3];
    const float* Wk = (const float*)d_in[4];
    const float* bk = (const float*)d_in[5];
    const float* Wv = (const float*)d_in[6];
    const float* bv = (const float*)d_in[7];
    const float* Wo = (const float*)d_in[8];
    const float* bo = (const float*)d_in[9];
    float* out = (float*)d_out;

    short* base = (short*)d_ws;
    short* xb   = base;                      // 4096*1024
    short* wqt  = xb  + 4194304;             // 512*1024
    short* wkt  = wqt + 524288;
    short* wvt  = wkt + 524288;
    short* wot  = wvt + 524288;              // 1024*512
    short* spW  = wot + 524288;              // 16*2048*64
    short* sqW  = spW + 2097152;
    short* vtW  = sqW + 2097152;             // [b,h,d,s]
    short* attB = vtW + 2097152;             // 4096*512
    // total = 14,680,064 shorts = 28 MB

    hipLaunchKernelGGL(convert_x, dim3(4096), dim3(256), 0, stream, xr, xi, xb);
    hipLaunchKernelGGL(transpose_w, dim3(32, 32, 4), dim3(256), 0, stream,
                       Wq, Wk, Wv, Wo, wqt, wkt, wvt, wot);
    hipLaunchKernelGGL(qkv_mfma, dim3(24, 32), dim3(128), 0, stream,
                       xb, wqt, wkt, wvt, bq, bk, bv, spW, sqW, vtW);
    hipLaunchKernelGGL(attn_mfma, dim3(32, 16), dim3(256), 0, stream,
                       spW, sqW, vtW, attB);
    hipLaunchKernelGGL(out_mfma, dim3(16, 32), dim3(128), 0, stream,
                       attB, wot, bo, out);
}